// Round 7
// baseline (115.631 us; speedup 1.0000x reference)
//
#include <hip/hip_runtime.h>

// Problem constants (fixed by reference)
constexpr int N_AG = 4096;
constexpr int M_CL = 256;
constexpr int KD   = 32;
constexpr float WEPS = 1e-6f;

// ws layout (floats). NOTE: harness poisons the FULL ws (268 MB -> 43 us
// fillBuffer per iteration, the top-5 censor) — not controllable from here.
constexpr int PART_STRIDE = 1088;              // [S2(1024) | S1(32) | Z | count | pad]
constexpr int VT_OFF = M_CL * 4 * PART_STRIDE; // vT (32 x 4096) k-major
constexpr int WT_OFF = VT_OFF + N_AG * KD;     // Wt (256 x 4096) masked

typedef __attribute__((ext_vector_type(8))) short short8;   // 8 bf16
typedef __attribute__((ext_vector_type(4))) float f32x4;

__device__ __forceinline__ float rlane(float x, int l) {
    return __int_as_float(__builtin_amdgcn_readlane(__float_as_int(x), l));
}
__device__ __forceinline__ short8 mk8(unsigned a, unsigned b, unsigned c, unsigned d) {
    union { unsigned u[4]; short8 s; } x;
    x.u[0] = a; x.u[1] = b; x.u[2] = c; x.u[3] = d;
    return x.s;
}

// ---------------------------------------------------------------------------
// K1: fused solve + W-transpose.
// Solve: 32x32 SPD GJ, TWO matrices per wave (col_a/col_b) — R6 inference:
// solve stuck ~35-40us with VALUBusy ~30% = latency-bound on the
// readlane->rcp->fma chain; two independent chains double ILP at equal
// issue. Template J keeps register indexing static (R4: dynamic col[j]
// forced scratch, VGPR=24, 50us).
// Result written straight to vT (k-major) via LDS repack.
// Tail: each block transposes+masks two 32x32 W tiles (kills the separate
// transpose dispatch).
// ---------------------------------------------------------------------------
template<int J>
struct GJ2 {
    static __device__ __forceinline__ void run(float (&ca)[32], float (&cb)[32]) {
        const float pa = rlane(ca[J], J);
        const float pb = rlane(cb[J], J);
        const float ia = 1.0f / pa;
        const float ib = 1.0f / pb;
        ca[J] *= ia;
        cb[J] *= ib;
        #pragma unroll
        for (int i = 0; i < 32; ++i) {
            if (i == J) continue;
            const float fa = rlane(ca[i], J);
            const float fb = rlane(cb[i], J);
            ca[i] = fmaf(-fa, ca[J], ca[i]);
            cb[i] = fmaf(-fb, cb[J], cb[i]);
        }
        GJ2<J + 1>::run(ca, cb);
    }
};
template<> struct GJ2<32> {
    static __device__ __forceinline__ void run(float (&)[32], float (&)[32]) {}
};

__global__ __launch_bounds__(256, 1) void solve_transpose_kernel(
        const float* __restrict__ oc, const float* __restrict__ mu,
        const float* __restrict__ W,
        float* __restrict__ vT, float* __restrict__ Wt) {
    __shared__ float res8[32][8];
    __shared__ float tb[32][33];

    const int t    = threadIdx.x;
    const int lane = t & 63;
    const int wv   = t >> 6;
    const int idx0 = blockIdx.x * 8;
    const int ia_  = idx0 + 2 * wv;
    const int ib_  = ia_ + 1;
    const int c = (lane < 32) ? lane : 32;

    float ca[32], cb[32];
    #pragma unroll
    for (int i = 0; i < 32; ++i) {
        ca[i] = (c < 32) ? oc[ia_ * 1024 + i * 32 + c] : mu[ia_ * 32 + i];
        cb[i] = (c < 32) ? oc[ib_ * 1024 + i * 32 + c] : mu[ib_ * 32 + i];
    }

    GJ2<0>::run(ca, cb);

    // distribute x (held by lane 32) to lane i, both matrices
    float ra = 0.0f, rb = 0.0f;
    #pragma unroll
    for (int i = 0; i < 32; ++i) {
        const float xa = rlane(ca[i], 32);
        const float xb = rlane(cb[i], 32);
        if (lane == i) { ra = xa; rb = xb; }
    }
    if (lane < 32) {
        res8[lane][2 * wv]     = ra;
        res8[lane][2 * wv + 1] = rb;
    }
    __syncthreads();
    {   // vT[k][idx0+j] : 8 consecutive n's per k-row
        const int k = t >> 3, j = t & 7;
        vT[(size_t)k * 4096 + idx0 + j] = res8[k][j];
    }

    // ---- two 32x32 W transpose tiles (masked) ----
    const int x = t & 31, y = t >> 5;
    #pragma unroll
    for (int rep = 0; rep < 2; ++rep) {
        const int tile = blockIdx.x * 2 + rep;
        const int n0 = (tile & 127) * 32;
        const int m0 = (tile >> 7) * 32;
        __syncthreads();
        #pragma unroll
        for (int r = 0; r < 4; ++r) {
            const int n = y + 8 * r;
            const float w = W[(size_t)(n0 + n) * 256 + m0 + x];
            tb[n][x] = (w >= WEPS) ? w : 0.0f;
        }
        __syncthreads();
        #pragma unroll
        for (int r = 0; r < 4; ++r) {
            const int mm = y + 8 * r;
            Wt[(size_t)(m0 + mm) * 4096 + n0 + x] = tb[x][mm];
        }
    }
}

// ---------------------------------------------------------------------------
// K2: partial weighted moments per (m,p) — ROUND-7: registers-only MFMA.
// R6 staged u through wave-private LDS (convert->ds_write->ds_read->MFMA);
// lgkm serialization kept it ~35us. Key: the 16x16x32 A/B fragment
// (lane l: rows l&15 and +16, k=n=(l>>4)*8+j) is DIRECTLY loadable from
// k-major vT as 2 float4/row — so: global float4 -> u=sqrt(w)*v -> hi/lo
// bf16 split (RTZ) -> MFMA, no LDS staging at all. S2 ~= Hh^T Hh + M + M^T,
// M = Hh^T Hl (quadrant scheme and epilogue identical to R6, which passed
// at absmax 0.5). LDS 43->21 KB -> 4 blocks/CU; loads pipeline freely.
// ---------------------------------------------------------------------------
__global__ __launch_bounds__(256, 4) void partial_kernel(const float* __restrict__ Wt,
                                                         const float* __restrict__ vT,
                                                         float* __restrict__ wsout) {
    const int m = blockIdx.x >> 2;
    const int p = blockIdx.x & 3;
    const int t = threadIdx.x;
    const int lane = t & 63;
    const int wv   = t >> 6;

    __shared__ float swbuf[1024];       // sqrt(w)
    __shared__ float sred[4 * 1024];    // per-wave C tiles, then cross-wave sum
    __shared__ float red[256];
    __shared__ float s1buf[32];

    // ---- w stage ----
    const float4 wv4 = reinterpret_cast<const float4*>(Wt + (size_t)m * 4096 + p * 1024)[t];
    const float zacc = wv4.x + wv4.y + wv4.z + wv4.w;
    const float cacc = (wv4.x >= WEPS ? 1.f : 0.f) + (wv4.y >= WEPS ? 1.f : 0.f)
                     + (wv4.z >= WEPS ? 1.f : 0.f) + (wv4.w >= WEPS ? 1.f : 0.f);
    reinterpret_cast<float4*>(swbuf)[t] =
        make_float4(sqrtf(wv4.x), sqrtf(wv4.y), sqrtf(wv4.z), sqrtf(wv4.w));
    if (t < 32) s1buf[t] = 0.0f;
    __syncthreads();

    const int a = lane & 15;           // fragment row (S2 rows a, a+16)
    const int g = lane >> 4;           // n-subgroup
    const int nl = wv * 256 + g * 8;   // block-local n base for this lane

    const float4* pa4 = reinterpret_cast<const float4*>(vT + (size_t)a * 4096 + p * 1024 + nl);
    const float4* pb4 = reinterpret_cast<const float4*>(vT + (size_t)(a + 16) * 4096 + p * 1024 + nl);

    f32x4 Chh[4], Chl[4];
    #pragma unroll
    for (int q = 0; q < 4; ++q) {
        Chh[q] = (f32x4){0.f, 0.f, 0.f, 0.f};
        Chl[q] = (f32x4){0.f, 0.f, 0.f, 0.f};
    }
    float s1a = 0.0f, s1b = 0.0f;

    #pragma unroll 2
    for (int ch = 0; ch < 8; ++ch) {
        const float4 va0 = pa4[ch * 8];
        const float4 va1 = pa4[ch * 8 + 1];
        const float4 vb0 = pb4[ch * 8];
        const float4 vb1 = pb4[ch * 8 + 1];
        const float4 s0  = *reinterpret_cast<const float4*>(&swbuf[nl + ch * 32]);
        const float4 s1v = *reinterpret_cast<const float4*>(&swbuf[nl + ch * 32 + 4]);

        // u = sqrt(w) * v, rows a and a+16
        const float ua0 = va0.x * s0.x,  ua1 = va0.y * s0.y;
        const float ua2 = va0.z * s0.z,  ua3 = va0.w * s0.w;
        const float ua4 = va1.x * s1v.x, ua5 = va1.y * s1v.y;
        const float ua6 = va1.z * s1v.z, ua7 = va1.w * s1v.w;
        const float ub0 = vb0.x * s0.x,  ub1 = vb0.y * s0.y;
        const float ub2 = vb0.z * s0.z,  ub3 = vb0.w * s0.w;
        const float ub4 = vb1.x * s1v.x, ub5 = vb1.y * s1v.y;
        const float ub6 = vb1.z * s1v.z, ub7 = vb1.w * s1v.w;

        // S1 partials: w*v = sqrt(w)*u
        s1a += s0.x*ua0 + s0.y*ua1 + s0.z*ua2 + s0.w*ua3
             + s1v.x*ua4 + s1v.y*ua5 + s1v.z*ua6 + s1v.w*ua7;
        s1b += s0.x*ub0 + s0.y*ub1 + s0.z*ub2 + s0.w*ub3
             + s1v.x*ub4 + s1v.y*ub5 + s1v.z*ub6 + s1v.w*ub7;

        // hi (RTZ bf16 = top 16 bits) and lo = u - hi
        #define BITS(u) __float_as_uint(u)
        #define LO(u)  ((u) - __uint_as_float(BITS(u) & 0xFFFF0000u))
        const short8 h0 = mk8(
            __builtin_amdgcn_perm(BITS(ua1), BITS(ua0), 0x07060302u),
            __builtin_amdgcn_perm(BITS(ua3), BITS(ua2), 0x07060302u),
            __builtin_amdgcn_perm(BITS(ua5), BITS(ua4), 0x07060302u),
            __builtin_amdgcn_perm(BITS(ua7), BITS(ua6), 0x07060302u));
        const short8 h1 = mk8(
            __builtin_amdgcn_perm(BITS(ub1), BITS(ub0), 0x07060302u),
            __builtin_amdgcn_perm(BITS(ub3), BITS(ub2), 0x07060302u),
            __builtin_amdgcn_perm(BITS(ub5), BITS(ub4), 0x07060302u),
            __builtin_amdgcn_perm(BITS(ub7), BITS(ub6), 0x07060302u));
        const float la0 = LO(ua0), la1 = LO(ua1), la2 = LO(ua2), la3 = LO(ua3);
        const float la4 = LO(ua4), la5 = LO(ua5), la6 = LO(ua6), la7 = LO(ua7);
        const float lb0 = LO(ub0), lb1 = LO(ub1), lb2 = LO(ub2), lb3 = LO(ub3);
        const float lb4 = LO(ub4), lb5 = LO(ub5), lb6 = LO(ub6), lb7 = LO(ub7);
        const short8 l0 = mk8(
            __builtin_amdgcn_perm(BITS(la1), BITS(la0), 0x07060302u),
            __builtin_amdgcn_perm(BITS(la3), BITS(la2), 0x07060302u),
            __builtin_amdgcn_perm(BITS(la5), BITS(la4), 0x07060302u),
            __builtin_amdgcn_perm(BITS(la7), BITS(la6), 0x07060302u));
        const short8 l1 = mk8(
            __builtin_amdgcn_perm(BITS(lb1), BITS(lb0), 0x07060302u),
            __builtin_amdgcn_perm(BITS(lb3), BITS(lb2), 0x07060302u),
            __builtin_amdgcn_perm(BITS(lb5), BITS(lb4), 0x07060302u),
            __builtin_amdgcn_perm(BITS(lb7), BITS(lb6), 0x07060302u));
        #undef BITS
        #undef LO

        Chh[0] = __builtin_amdgcn_mfma_f32_16x16x32_bf16(h0, h0, Chh[0], 0, 0, 0);
        Chh[1] = __builtin_amdgcn_mfma_f32_16x16x32_bf16(h0, h1, Chh[1], 0, 0, 0);
        Chh[2] = __builtin_amdgcn_mfma_f32_16x16x32_bf16(h1, h0, Chh[2], 0, 0, 0);
        Chh[3] = __builtin_amdgcn_mfma_f32_16x16x32_bf16(h1, h1, Chh[3], 0, 0, 0);
        Chl[0] = __builtin_amdgcn_mfma_f32_16x16x32_bf16(h0, l0, Chl[0], 0, 0, 0);
        Chl[1] = __builtin_amdgcn_mfma_f32_16x16x32_bf16(h0, l1, Chl[1], 0, 0, 0);
        Chl[2] = __builtin_amdgcn_mfma_f32_16x16x32_bf16(h1, l0, Chl[2], 0, 0, 0);
        Chl[3] = __builtin_amdgcn_mfma_f32_16x16x32_bf16(h1, l1, Chl[3], 0, 0, 0);
    }

    // ---- S1: reduce over the 4 n-subgroups (lanes sharing a) ----
    s1a += __shfl_xor(s1a, 16); s1a += __shfl_xor(s1a, 32);
    s1b += __shfl_xor(s1b, 16); s1b += __shfl_xor(s1b, 32);
    if (lane < 16) {
        atomicAdd(&s1buf[a], s1a);
        atomicAdd(&s1buf[a + 16], s1b);
    }

    // ---- epilogue: per-wave C tile with symmetrized cross term ----
    float* rw = &sred[wv * 1024];
    #pragma unroll
    for (int q = 0; q < 4; ++q) {
        const int I = q >> 1, J = q & 1;
        #pragma unroll
        for (int r = 0; r < 4; ++r) {
            const int ar = I * 16 + (lane >> 4) * 4 + r;
            const int br = J * 16 + (lane & 15);
            rw[ar * 32 + br] = Chh[q][r] + Chl[q][r];
        }
    }
    __syncthreads();
    #pragma unroll
    for (int q = 0; q < 4; ++q) {
        const int I = q >> 1, J = q & 1;
        #pragma unroll
        for (int r = 0; r < 4; ++r) {
            const int ar = I * 16 + (lane >> 4) * 4 + r;
            const int br = J * 16 + (lane & 15);
            rw[br * 32 + ar] += Chl[q][r];
        }
    }
    __syncthreads();

    // ---- cross-wave sum + record write ----
    const size_t base = (size_t)(m * 4 + p) * PART_STRIDE;
    float o0 = 0.f, o1 = 0.f, o2 = 0.f, o3 = 0.f;
    #pragma unroll
    for (int ww = 0; ww < 4; ++ww) {
        const float4 x = *reinterpret_cast<const float4*>(&sred[ww * 1024 + t * 4]);
        o0 += x.x; o1 += x.y; o2 += x.z; o3 += x.w;
    }
    *reinterpret_cast<float4*>(&wsout[base + t * 4]) = make_float4(o0, o1, o2, o3);

    // ---- Z / count ----
    red[t] = zacc; __syncthreads();
    #pragma unroll
    for (int s = 128; s > 0; s >>= 1) {
        if (t < s) red[t] += red[t + s];
        __syncthreads();
    }
    if (t == 0) wsout[base + 1056] = red[0];
    __syncthreads();
    red[t] = cacc; __syncthreads();
    #pragma unroll
    for (int s = 128; s > 0; s >>= 1) {
        if (t < s) red[t] += red[t + s];
        __syncthreads();
    }
    if (t == 0) wsout[base + 1057] = red[0];
    if (t < 32) wsout[base + 1024 + t] = s1buf[t];
}

// ---------------------------------------------------------------------------
// K3: combine. One block per m.
//   G = op^T op ; psi = tr(G S2)/Z - vbar^T G vbar ; gate count>=2
// ---------------------------------------------------------------------------
__global__ __launch_bounds__(256) void combine_kernel(const float* __restrict__ op,
                                                      const float* __restrict__ ws,
                                                      float* __restrict__ out) {
    const int m = blockIdx.x;
    const int t = threadIdx.x;

    __shared__ float omg[32 * 33];
    __shared__ float vbar[32];
    __shared__ float red[256];

    #pragma unroll
    for (int i = 0; i < 4; ++i) {
        const int g = t + 256 * i;
        const int r = g >> 5, cc = g & 31;
        omg[r * 33 + cc] = op[(size_t)m * 1024 + g];
    }

    const size_t mb = (size_t)m * 4 * PART_STRIDE;
    float Z = 0.0f, cnt = 0.0f, s1 = 0.0f;
    float s2[4] = {0.f, 0.f, 0.f, 0.f};
    #pragma unroll
    for (int p2 = 0; p2 < 4; ++p2) {
        const size_t bp = mb + (size_t)p2 * PART_STRIDE;
        Z   += ws[bp + 1056];
        cnt += ws[bp + 1057];
        if (t < 32) s1 += ws[bp + 1024 + t];
        const float4 sp = *reinterpret_cast<const float4*>(&ws[bp + t * 4]);
        s2[0] += sp.x; s2[1] += sp.y; s2[2] += sp.z; s2[3] += sp.w;
    }
    const float invZ = 1.0f / fmaxf(Z, 1e-30f);
    if (t < 32) vbar[t] = s1 * invZ;
    __syncthreads();

    const int k  = t >> 3;
    const int l0 = (t & 7) * 4;
    float G[4] = {0.f, 0.f, 0.f, 0.f};
    #pragma unroll
    for (int i = 0; i < 32; ++i) {
        const float ok = omg[i * 33 + k];
        #pragma unroll
        for (int q = 0; q < 4; ++q) G[q] = fmaf(ok, omg[i * 33 + l0 + q], G[q]);
    }

    const float vk = vbar[k];
    float val = 0.0f;
    #pragma unroll
    for (int q = 0; q < 4; ++q)
        val += G[q] * (s2[q] * invZ - vk * vbar[l0 + q]);

    red[t] = val; __syncthreads();
    #pragma unroll
    for (int s = 128; s > 0; s >>= 1) {
        if (t < s) red[t] += red[t + s];
        __syncthreads();
    }
    if (t == 0) out[m] = (cnt >= 1.5f) ? red[0] : 0.0f;
}

// ---------------------------------------------------------------------------
extern "C" void kernel_launch(void* const* d_in, const int* in_sizes, int n_in,
                              void* d_out, int out_size, void* d_ws, size_t ws_size,
                              hipStream_t stream) {
    const float* W  = (const float*)d_in[0];  // (4096, 256)
    const float* mu = (const float*)d_in[1];  // (4096, 32)
    const float* oc = (const float*)d_in[2];  // (4096, 32, 32)
    const float* op = (const float*)d_in[3];  // (256, 32, 32)
    float* out = (float*)d_out;               // (256,)
    float* ws  = (float*)d_ws;

    solve_transpose_kernel<<<512, 256, 0, stream>>>(oc, mu, W, ws + VT_OFF, ws + WT_OFF);
    partial_kernel<<<1024, 256, 0, stream>>>(ws + WT_OFF, ws + VT_OFF, ws);
    combine_kernel<<<256, 256, 0, stream>>>(op, ws, out);
}